// Round 7
// baseline (2784.079 us; speedup 1.0000x reference)
//
#include <hip/hip_runtime.h>
#include <cstdint>

#define S64 64
#define S3 (S64*S64*S64)
#define NB 8
#define NPTS 2048

typedef unsigned short ushort_t;
typedef __attribute__((ext_vector_type(8))) short bh8;    // 8 bf16 (4 VGPRs)
typedef __attribute__((ext_vector_type(4))) float f4v;    // 4 fp32 acc

// ---- bf16 split helpers: a ~= hi + lo, each bf16 (RNE) ----
__device__ inline ushort_t bf_rne(float a) {
    unsigned u = __float_as_uint(a);
    unsigned r = (u + 0x7FFFu + ((u >> 16) & 1u)) >> 16;
    return (ushort_t)r;
}
__device__ inline void split2(float a, ushort_t& h, ushort_t& lo) {
    h = bf_rne(a);
    float hf = __uint_as_float(((unsigned)h) << 16);
    lo = bf_rne(a - hf);
}

// ---------------- Kernel 1: completion + gridding_reverse ----------------
__global__ void k_gridding(const float* __restrict__ data, float* __restrict__ pt_buf) {
    int idx = blockIdx.x * blockDim.x + threadIdx.x;
    if (idx >= NB * S3) return;
    int b = idx / S3;
    int cell = idx - b * S3;
    int i = cell >> 12;
    int j = (cell >> 6) & 63;
    int k = cell & 63;
    const float* db = data + (size_t)b * S3;
    float wsum = 0.f, px = 0.f, py = 0.f, pz = 0.f;
#pragma unroll
    for (int dx = 0; dx < 2; ++dx)
#pragma unroll
    for (int dy = 0; dy < 2; ++dy)
#pragma unroll
    for (int dz = 0; dz < 2; ++dz) {
        int xi = i + dx - 1, yj = j + dy - 1, zk = k + dz - 1;
        float w = 0.f;
        if (xi >= 0 && yj >= 0 && zk >= 0) {
            float v = db[((xi << 6) + yj << 6) + zk];
            w = (fabsf(v) <= 1.0f) ? 1.0f : 0.0f;
        }
        px += w * (float)xi;
        py += w * (float)yj;
        pz += w * (float)zk;
        wsum += w;
    }
    float wc = fmaxf(wsum, 1e-8f);
    float ptx = (px / wc) / 32.0f - 1.0f;
    float pty = (py / wc) / 32.0f - 1.0f;
    float ptz = (pz / wc) / 32.0f - 1.0f;
    if (!(wsum > 0.f)) { ptx = 0.f; pty = 0.f; ptz = 0.f; }
    float* o = pt_buf + (size_t)b * (S3 * 3) + (size_t)cell * 3;
    o[0] = ptx; o[1] = pty; o[2] = ptz;
}

// ---------------- Kernel 2: maxpool 4x4x4 ----------------
__global__ void k_maxpool(const float* __restrict__ pt_buf, float* __restrict__ pooled) {
    int idx = blockIdx.x * blockDim.x + threadIdx.x;
    if (idx >= NB * 12288) return;
    int b = idx / 12288;
    int r = idx - b * 12288;
    int c = r >> 12;
    int r2 = r & 4095;
    int X = r2 >> 8;
    int Y = (r2 >> 4) & 15;
    int Z = r2 & 15;
    const float* src = pt_buf + (size_t)b * (S3 * 3) + (size_t)c * S3;
    float m = -INFINITY;
#pragma unroll
    for (int u = 0; u < 4; ++u)
#pragma unroll
    for (int v = 0; v < 4; ++v)
#pragma unroll
    for (int w = 0; w < 4; ++w) {
        float val = src[((4 * X + u) << 12) + ((4 * Y + v) << 6) + (4 * Z + w)];
        m = fmaxf(m, val);
    }
    pooled[idx] = m;
}

// ---------------- Kernel 3: masked top-k + gather ----------------
__global__ void k_topk(const float* __restrict__ pooled, const float* __restrict__ noise,
                       float* __restrict__ sc) {
    __shared__ unsigned long long keys[4096];
    int b = blockIdx.x;
    int tid = threadIdx.x;
    for (int p = tid; p < 4096; p += 1024) {
        const float* cp = pooled + (size_t)b * 12288 + (size_t)p * 3;
        float ssum = (cp[0] + cp[1]) + cp[2];
        float score = (ssum != 0.0f) ? noise[b * 4096 + p] : -1e30f;
        unsigned int u = __float_as_uint(score);
        unsigned int s = (u & 0x80000000u) ? ~u : (u | 0x80000000u);
        keys[p] = ((unsigned long long)(~s) << 32) | (unsigned int)p;
    }
    __syncthreads();
    for (int k = 2; k <= 4096; k <<= 1) {
        for (int j = k >> 1; j > 0; j >>= 1) {
            for (int t = tid; t < 4096; t += 1024) {
                int ixj = t ^ j;
                if (ixj > t) {
                    bool up = ((t & k) == 0);
                    unsigned long long a = keys[t], c = keys[ixj];
                    if (up ? (a > c) : (a < c)) { keys[t] = c; keys[ixj] = a; }
                }
            }
            __syncthreads();
        }
    }
    for (int r = tid; r < NPTS; r += 1024) {
        int p = (int)(keys[r] & 0xFFFFFFFFu);
        const float* cp = pooled + (size_t)b * 12288 + (size_t)p * 3;
        float* o = sc + ((size_t)b * NPTS + r) * 3;
        o[0] = cp[0]; o[1] = cp[1]; o[2] = cp[2];
    }
}

// ---------------- Kernel 4: cubic feature sampling -> A' part triples ----------------
__global__ void k_cubic(const float* __restrict__ sc,
                        const float* __restrict__ s32,
                        const float* __restrict__ s16,
                        const float* __restrict__ s8,
                        ushort_t* __restrict__ Ap, int row0) {
    int rl = blockIdx.y;
    int row = row0 + rl;
    int col = blockIdx.x * 256 + threadIdx.x;  // 0..1791
    int b = row >> 11;
    const float* p = sc + (size_t)row * 3;
    float ptx = p[0], pty = p[1], ptz = p[2];
    const float* feat;
    int S, c, q;
    if (col < 256)      { S = 32; q = col >> 5;  c = col & 31;
                          feat = s32 + (size_t)b * 32 * 32768; }
    else if (col < 768) { int cc = col - 256; S = 16; q = cc >> 6; c = cc & 63;
                          feat = s16 + (size_t)b * 64 * 4096; }
    else                { int cc = col - 768; S = 8;  q = cc >> 7; c = cc & 127;
                          feat = s8 + (size_t)b * 128 * 512; }
    int dx = (q >> 2) & 1, dy = (q >> 1) & 1, dz = q & 1;
    float half = 0.5f * (float)S;
    int lx = (int)floorf((ptx + 1.0f) * half);
    int ly = (int)floorf((pty + 1.0f) * half);
    int lz = (int)floorf((ptz + 1.0f) * half);
    int ix = min(max(lx + dx, 0), S - 1);
    int iy = min(max(ly + dy, 0), S - 1);
    int iz = min(max(lz + dz, 0), S - 1);
    int lin = (ix * S + iy) * S + iz;
    float v = feat[(size_t)c * S * S * S + lin];
    ushort_t h, lo; split2(v, h, lo);
    size_t base = (size_t)rl * 5376 + 3 * (size_t)col;
    Ap[base] = h; Ap[base + 1] = h; Ap[base + 2] = lo;
}

// ---------------- split-convert: W[K][N] fp32 -> Bp[Npad][3K] (hi,lo,hi) ----------------
__global__ void k_split_transpose(const float* __restrict__ W, ushort_t* __restrict__ Bp,
                                  int K, int N, int Npad) {
    __shared__ float t[32][33];
    int tx = threadIdx.x, ty = threadIdx.y;   // (32,8)
    int n0 = blockIdx.x * 32, k0 = blockIdx.y * 32;
#pragma unroll
    for (int kk = 0; kk < 4; ++kk) {
        int k = k0 + ty + kk * 8, n = n0 + tx;
        float v = (k < K && n < N) ? W[(size_t)k * N + n] : 0.f;
        t[ty + kk * 8][tx] = v;
    }
    __syncthreads();
    size_t Kp = 3 * (size_t)K;
#pragma unroll
    for (int nn = 0; nn < 4; ++nn) {
        int n = n0 + ty + nn * 8;
        int k = k0 + tx;
        if (n >= Npad || k >= K) continue;
        float a = t[tx][ty + nn * 8];
        ushort_t h, lo; split2(a, h, lo);
        size_t base = (size_t)n * Kp + 3 * (size_t)k;
        Bp[base] = h; Bp[base + 1] = lo; Bp[base + 2] = h;
    }
}

// ---------------- split-convert rows: src[R][K] -> dst[R][3K], trip B (hi,lo,hi) --------
__global__ void k_split_rows_b(const float* __restrict__ src, ushort_t* __restrict__ dst, int K) {
    int r = blockIdx.y;
    int k = blockIdx.x * 256 + threadIdx.x;
    if (k >= K) return;
    float a = src[(size_t)r * K + k];
    ushort_t h, lo; split2(a, h, lo);
    size_t base = (size_t)r * (3 * (size_t)K) + 3 * (size_t)k;
    dst[base] = h; dst[base + 1] = lo; dst[base + 2] = h;
}

// ---------------- generic im2col + split (conv A-side) ----------------
__global__ void k_split_im2col(const float* __restrict__ src, ushort_t* __restrict__ Ap,
                               int Cin, int Kin) {
    int mp = blockIdx.y;                       // 0..895
    int k = blockIdx.x * 256 + threadIdx.x;
    if (k >= Kin) return;
    float v = 0.f;
    if (mp < 800) {
        int b = mp / 100, h = mp - b * 100;
        int c = k / 3, t = k - c * 3;
        int hh = h + t - 1;
        if (hh >= 0 && hh < 100)
            v = src[((size_t)b * Cin + c) * 100 + hh];
    }
    ushort_t h16, lo; split2(v, h16, lo);
    size_t base = (size_t)mp * (3 * (size_t)Kin) + 3 * (size_t)k;
    Ap[base] = h16; Ap[base + 1] = h16; Ap[base + 2] = lo;
}

// ---------------- zero kernel ----------------
__global__ void k_zero(float* __restrict__ p, int n) {
    int i = blockIdx.x * 256 + threadIdx.x;
    if (i < n) p[i] = 0.f;
}

// ---------------- epilogue for split-K accumulators ----------------
// mode 0: Cf[m*N+n] fp32; mode 1: conv layout; mode 2: triple-bf16 (hi,hi,lo) to Cs
__global__ void k_epi(const float* __restrict__ acc, const float* __restrict__ bias,
                      const float* __restrict__ bn_g, const float* __restrict__ bn_b,
                      const float* __restrict__ bn_m, const float* __restrict__ bn_v,
                      float* __restrict__ Cf, ushort_t* __restrict__ Cs,
                      int M, int N, int ldc, int relu, int dobn, int mode) {
    int idx = blockIdx.x * 256 + threadIdx.x;
    if (idx >= M * N) return;
    int m = idx / N, n = idx - m * N;
    float v = acc[idx] + bias[n];
    if (dobn) {
        float inv = rsqrtf(bn_v[n] + 1e-5f) * bn_g[n];
        v = v * inv + (bn_b[n] - bn_m[n] * inv);
    }
    if (relu) v = fmaxf(v, 0.f);
    if (mode == 0) {
        Cf[idx] = v;
    } else if (mode == 1) {
        int b = m / 100, h = m - b * 100;
        Cf[((size_t)b * N + n) * 100 + h] = v;
    } else {
        ushort_t h, lo; split2(v, h, lo);
        size_t base = (size_t)m * ldc + 3 * (size_t)n;
        Cs[base] = h; Cs[base + 1] = h; Cs[base + 2] = lo;
    }
}

// ---------------- MFMA bf16 GEMM, 2-phase dbuf + LDS XOR-swizzle + split-K ----------------
// Swizzle (rule #21 both-sides): LDS dest stays linear; global SOURCE quad is
// pre-swizzled (lc ^ (lr>>2)&3) so LDS[r][q] = G[r][q ^ ((r>>2)&3)]; reads use
// physical quad pq = jq ^ ((fr>>2)&3). 16 lanes -> 8 distinct 4-bank groups,
// 2 lanes each = conflict-free (2-way is free, m136).
#define GLDS(g, s) __builtin_amdgcn_global_load_lds( \
    (const __attribute__((address_space(1))) void*)(g), \
    (__attribute__((address_space(3))) void*)(s), 16, 0, 0)

__global__ __launch_bounds__(256) void k_gemm_mfma(
    const ushort_t* __restrict__ Ap, const ushort_t* __restrict__ Bp,
    const float* __restrict__ bias,
    const float* __restrict__ bn_g, const float* __restrict__ bn_b,
    const float* __restrict__ bn_m, const float* __restrict__ bn_v,
    float* __restrict__ Cf, ushort_t* __restrict__ Cs,
    int M, int N, int Kp, int ldc,
    int relu, int dobn, int omode, int osplit,
    int ks, int Kc)
{
    __shared__ short As[2][128][32];
    __shared__ short Bs[2][128][32];
    int tid = threadIdx.x;
    int l = tid & 63, w = tid >> 6;
    int wr = w >> 1, wc = w & 1;
    int m0 = blockIdx.y * 128, n0 = blockIdx.x * 128;
    int kbeg = blockIdx.z * Kc;       // Kc multiple of 32; ks*Kc == Kp

    f4v acc[4][4];
#pragma unroll
    for (int i = 0; i < 4; ++i)
#pragma unroll
        for (int j = 0; j < 4; ++j) acc[i][j] = (f4v){0.f, 0.f, 0.f, 0.f};

    int lr = l >> 2;                  // row within 16-row chunk
    int lc = l & 3;                   // logical 16B quad within 64B row
    int lcs = lc ^ ((lr >> 2) & 3);   // swizzled source quad
    const ushort_t* pa0 = Ap + (size_t)(m0 + w * 32 + lr) * Kp + lcs * 8 + kbeg;
    const ushort_t* pa1 = pa0 + (size_t)16 * Kp;
    const ushort_t* pb0 = Bp + (size_t)(n0 + w * 32 + lr) * Kp + lcs * 8 + kbeg;
    const ushort_t* pb1 = pb0 + (size_t)16 * Kp;

    int fr = l & 15;                          // fragment row/col index
    int ko = ((l >> 4) ^ ((fr >> 2) & 3)) * 8;  // swizzled LDS k-offset (elements)
    int nt = Kc >> 5;                         // tiles in this chunk

    // prologue: stage tile 0 into buffer 0
    GLDS(pa0, &As[0][w * 32][0]);
    GLDS(pa1, &As[0][w * 32 + 16][0]);
    GLDS(pb0, &Bs[0][w * 32][0]);
    GLDS(pb1, &Bs[0][w * 32 + 16][0]);
    __syncthreads();

    for (int t = 0; t < nt; ++t) {
        int cur = t & 1;
        if (t + 1 < nt) {
            int ko2 = (t + 1) << 5;
            GLDS(pa0 + ko2, &As[cur ^ 1][w * 32][0]);
            GLDS(pa1 + ko2, &As[cur ^ 1][w * 32 + 16][0]);
            GLDS(pb0 + ko2, &Bs[cur ^ 1][w * 32][0]);
            GLDS(pb1 + ko2, &Bs[cur ^ 1][w * 32 + 16][0]);
        }
        bh8 af[4], bfr[4];
#pragma unroll
        for (int i = 0; i < 4; ++i)
            af[i] = *reinterpret_cast<const bh8*>(&As[cur][wr * 64 + i * 16 + fr][ko]);
#pragma unroll
        for (int j = 0; j < 4; ++j)
            bfr[j] = *reinterpret_cast<const bh8*>(&Bs[cur][wc * 64 + j * 16 + fr][ko]);
#pragma unroll
        for (int i = 0; i < 4; ++i)
#pragma unroll
            for (int j = 0; j < 4; ++j)
                acc[i][j] = __builtin_amdgcn_mfma_f32_16x16x32_bf16(af[i], bfr[j], acc[i][j], 0, 0, 0);
        __syncthreads();
    }

    // epilogue: C/D mapping col=lane&15, row=(lane>>4)*4+reg  [verified m89/m91]
#pragma unroll
    for (int i = 0; i < 4; ++i)
#pragma unroll
        for (int j = 0; j < 4; ++j) {
#pragma unroll
            for (int r = 0; r < 4; ++r) {
                int m = m0 + wr * 64 + i * 16 + (l >> 4) * 4 + r;
                int n = n0 + wc * 64 + j * 16 + fr;
                if (m >= M || n >= N) continue;
                if (ks > 1) {
                    atomicAdd(&Cf[(size_t)m * N + n], acc[i][j][r]);
                    continue;
                }
                float v = acc[i][j][r] + bias[n];
                if (dobn) {
                    float inv = rsqrtf(bn_v[n] + 1e-5f) * bn_g[n];
                    v = v * inv + (bn_b[n] - bn_m[n] * inv);
                }
                if (relu) v = fmaxf(v, 0.f);
                if (osplit) {
                    ushort_t h, lo; split2(v, h, lo);
                    size_t base = (size_t)m * ldc + 3 * (size_t)n;
                    Cs[base] = h; Cs[base + 1] = h; Cs[base + 2] = lo;
                } else if (omode == 0) {
                    Cf[(size_t)m * N + n] = v;
                } else {
                    int bb = m / 100, h = m - bb * 100;
                    Cf[((size_t)bb * N + n) * 100 + h] = v;
                }
            }
        }
}

// ---------------- skinny GEMM for M=8 final FCs ----------------
__global__ __launch_bounds__(256) void k_skinny(
    const float* __restrict__ A, const float* __restrict__ B,
    const float* __restrict__ bias, float* __restrict__ C,
    int M, int N, int K, int relu)
{
    int n = blockIdx.x * 64 + (threadIdx.x & 63);
    int m = blockIdx.y * 4 + (threadIdx.x >> 6);
    if (m >= M || n >= N) return;
    const float* a = A + (size_t)m * K;
    const float* b = B + n;
    float acc = 0.f;
    int k = 0;
#pragma unroll 8
    for (; k + 8 <= K; k += 8) {
#pragma unroll
        for (int u = 0; u < 8; ++u)
            acc = fmaf(a[k + u], b[(size_t)(k + u) * N], acc);
    }
    for (; k < K; ++k) acc = fmaf(a[k], b[(size_t)k * N], acc);
    float v = acc + bias[n];
    if (relu) v = fmaxf(v, 0.f);
    C[(size_t)m * N + n] = v;
}

// ---------------- launch ----------------
extern "C" void kernel_launch(void* const* d_in, const int* in_sizes, int n_in,
                              void* d_out, int out_size, void* d_ws, size_t ws_size,
                              hipStream_t stream) {
    const float* data  = (const float*)d_in[0];
    const float* s32   = (const float*)d_in[1];
    const float* s16   = (const float*)d_in[2];
    const float* s8    = (const float*)d_in[3];
    const float* noise = (const float*)d_in[4];
    const float* w11 = (const float*)d_in[5];  const float* b11 = (const float*)d_in[6];
    const float* w12 = (const float*)d_in[7];  const float* b12 = (const float*)d_in[8];
    const float* w13 = (const float*)d_in[9];  const float* b13 = (const float*)d_in[10];
    const float* c1w = (const float*)d_in[11]; const float* c1b = (const float*)d_in[12];
    const float* g1 = (const float*)d_in[13];  const float* be1 = (const float*)d_in[14];
    const float* m1 = (const float*)d_in[15];  const float* v1  = (const float*)d_in[16];
    const float* c2w = (const float*)d_in[17]; const float* c2b = (const float*)d_in[18];
    const float* g2 = (const float*)d_in[19];  const float* be2 = (const float*)d_in[20];
    const float* m2 = (const float*)d_in[21];  const float* v2  = (const float*)d_in[22];
    const float* c3w = (const float*)d_in[23]; const float* c3b = (const float*)d_in[24];
    const float* g3 = (const float*)d_in[25];  const float* be3 = (const float*)d_in[26];
    const float* m3 = (const float*)d_in[27];  const float* v3  = (const float*)d_in[28];
    const float* c4w = (const float*)d_in[29]; const float* c4b = (const float*)d_in[30];
    const float* g4 = (const float*)d_in[31];  const float* be4 = (const float*)d_in[32];
    const float* m4 = (const float*)d_in[33];  const float* v4  = (const float*)d_in[34];
    const float* w15a = (const float*)d_in[35]; const float* b15a = (const float*)d_in[36];
    const float* w15b = (const float*)d_in[37]; const float* b15b = (const float*)d_in[38];
    const float* w15c = (const float*)d_in[39]; const float* b15c = (const float*)d_in[40];
    float* out = (float*)d_out;
    (void)in_sizes; (void)n_in; (void)out_size;

    char* ws = (char*)d_ws;

    // adaptive partition: halves (P=8192, ~251MB) if ws fits, else quarters (P=4096, ~145MB)
    size_t offs[16];
    auto plan = [&](size_t P, size_t* o) -> size_t {
        size_t off = 0;
        auto al = [&](size_t b) { size_t x = off; off += (b + 255) & ~(size_t)255; return x; };
        o[0]  = al(P * 5376 * 2);          // rA: pt_buf -> A' part -> conv A' triples
        o[1]  = al(P * 5376 * 2);          // rF: f2' part -> conv B' triples
        o[2]  = al(P * 1344 * 2);          // rG: f3' part (FC3 A-triples)
        o[3]  = al((size_t)1792 * 5376 * 2); // B'1
        o[4]  = al((size_t)512 * 5376 * 2);  // B'2
        o[5]  = al((size_t)128 * 1344 * 2);  // B'3
        o[6]  = al(P * 448 * 4);           // split-K accumulator (>= 800*1024*4)
        o[7]  = al((size_t)16384 * 100 * 4); // f4
        o[8]  = al((size_t)NB * 1024 * 100 * 4); // y1
        o[9]  = al((size_t)NB * 512 * 100 * 4);  // y2
        o[10] = al((size_t)NB * 128 * 100 * 4);  // y3
        o[11] = al((size_t)NB * 32 * 100 * 4);   // y4
        o[12] = al(NB * 12288 * 4);        // pooled
        o[13] = al(NB * NPTS * 3 * 4);     // sc
        o[14] = al(NB * 512 * 4);          // h2
        o[15] = al(NB * 128 * 4);          // h3
        return off;
    };
    size_t P = 8192;
    if (plan(P, offs) > ws_size) P = 4096;
    plan(P, offs);
    int nparts = (int)(16384 / P);
    int Pb = (int)(P / 128);                  // row blocks per part
    int ksFC2 = (P == 8192) ? 2 : 4;
    int KcFC2 = 5376 / ksFC2;

    float*    pt_buf = (float*)(ws + offs[0]);
    ushort_t* Aq     = (ushort_t*)(ws + offs[0]);
    ushort_t* Aconv  = (ushort_t*)(ws + offs[0]);
    ushort_t* Fq     = (ushort_t*)(ws + offs[1]);
    ushort_t* Bconv  = (ushort_t*)(ws + offs[1]);
    ushort_t* Gq     = (ushort_t*)(ws + offs[2]);
    ushort_t* Bp1    = (ushort_t*)(ws + offs[3]);
    ushort_t* Bp2    = (ushort_t*)(ws + offs[4]);
    ushort_t* Bp3    = (ushort_t*)(ws + offs[5]);
    float*    Cacc   = (float*)(ws + offs[6]);
    float* f4     = (float*)(ws + offs[7]);
    float* y1     = (float*)(ws + offs[8]);
    float* y2     = (float*)(ws + offs[9]);
    float* y3     = (float*)(ws + offs[10]);
    float* y4     = (float*)(ws + offs[11]);
    float* pooled = (float*)(ws + offs[12]);
    float* scb    = (float*)(ws + offs[13]);
    float* h2     = (float*)(ws + offs[14]);
    float* h3     = (float*)(ws + offs[15]);

    // front-end
    k_gridding<<<(NB * S3 + 255) / 256, 256, 0, stream>>>(data, pt_buf);
    k_maxpool<<<(NB * 12288 + 255) / 256, 256, 0, stream>>>(pt_buf, pooled);
    k_topk<<<NB, 1024, 0, stream>>>(pooled, noise, scb);

    // weight triples for FC1..FC3
    k_split_transpose<<<dim3(56, 56), dim3(32, 8), 0, stream>>>(w11, Bp1, 1792, 1792, 1792);
    k_split_transpose<<<dim3(16, 56), dim3(32, 8), 0, stream>>>(w12, Bp2, 1792, 448, 512);
    k_split_transpose<<<dim3(4, 14),  dim3(32, 8), 0, stream>>>(w13, Bp3, 448, 100, 128);

    // FC1 + FC2 + FC3 in parts of P rows
    for (int q = 0; q < nparts; ++q) {
        k_cubic<<<dim3(7, (unsigned)P), 256, 0, stream>>>(scb, s32, s16, s8, Aq, q * (int)P);
        // FC1: direct, triple-bf16 out
        k_gemm_mfma<<<dim3(14, Pb), 256, 0, stream>>>(Aq, Bp1, b11,
            nullptr, nullptr, nullptr, nullptr, nullptr, Fq,
            (int)P, 1792, 5376, 5376, 1, 0, 0, 1, 1, 5376);
        // FC2: split-K, epilogue -> Gq triples
        k_zero<<<((int)P * 448 + 255) / 256, 256, 0, stream>>>(Cacc, (int)P * 448);
        k_gemm_mfma<<<dim3(4, Pb, ksFC2), 256, 0, stream>>>(Fq, Bp2, nullptr,
            nullptr, nullptr, nullptr, nullptr, Cacc, nullptr,
            (int)P, 448, 5376, 0, 0, 0, 0, 0, ksFC2, KcFC2);
        k_epi<<<((int)P * 448 + 255) / 256, 256, 0, stream>>>(Cacc, b12,
            nullptr, nullptr, nullptr, nullptr, nullptr, Gq,
            (int)P, 448, 1344, 1, 0, 2);
        // FC3: split-K x6, epilogue -> f4 slice fp32
        k_zero<<<((int)P * 100 + 255) / 256, 256, 0, stream>>>(Cacc, (int)P * 100);
        k_gemm_mfma<<<dim3(1, Pb, 6), 256, 0, stream>>>(Gq, Bp3, nullptr,
            nullptr, nullptr, nullptr, nullptr, Cacc, nullptr,
            (int)P, 100, 1344, 0, 0, 0, 0, 0, 6, 224);
        k_epi<<<((int)P * 100 + 255) / 256, 256, 0, stream>>>(Cacc, b13,
            nullptr, nullptr, nullptr, nullptr, f4 + (size_t)q * P * 100, nullptr,
            (int)P, 100, 0, 1, 0, 0);
    }

    // conv1: Cin=2048 Kin=6144, split-K x8 (448 blocks)
    k_split_im2col<<<dim3(24, 896), 256, 0, stream>>>(f4, Aconv, 2048, 6144);
    k_split_rows_b<<<dim3(24, 1024), 256, 0, stream>>>(c1w, Bconv, 6144);
    k_zero<<<(800 * 1024 + 255) / 256, 256, 0, stream>>>(Cacc, 800 * 1024);
    k_gemm_mfma<<<dim3(8, 7, 8), 256, 0, stream>>>(Aconv, Bconv, nullptr,
        nullptr, nullptr, nullptr, nullptr, Cacc, nullptr,
        800, 1024, 18432, 0, 0, 0, 0, 0, 8, 2304);
    k_epi<<<(800 * 1024 + 255) / 256, 256, 0, stream>>>(Cacc, c1b,
        g1, be1, m1, v1, y1, nullptr, 800, 1024, 0, 1, 1, 1);

    // conv2: Cin=1024 Kin=3072, split-K x8 (224 blocks)
    k_split_im2col<<<dim3(12, 896), 256, 0, stream>>>(y1, Aconv, 1024, 3072);
    k_split_rows_b<<<dim3(12, 512), 256, 0, stream>>>(c2w, Bconv, 3072);
    k_zero<<<(800 * 512 + 255) / 256, 256, 0, stream>>>(Cacc, 800 * 512);
    k_gemm_mfma<<<dim3(4, 7, 8), 256, 0, stream>>>(Aconv, Bconv, nullptr,
        nullptr, nullptr, nullptr, nullptr, Cacc, nullptr,
        800, 512, 9216, 0, 0, 0, 0, 0, 8, 1152);
    k_epi<<<(800 * 512 + 255) / 256, 256, 0, stream>>>(Cacc, c2b,
        g2, be2, m2, v2, y2, nullptr, 800, 512, 0, 1, 1, 1);

    // conv3: Cin=512 Kin=1536, split-K x16 (112 blocks)
    k_split_im2col<<<dim3(6, 896), 256, 0, stream>>>(y2, Aconv, 512, 1536);
    k_split_rows_b<<<dim3(6, 128), 256, 0, stream>>>(c3w, Bconv, 1536);
    k_zero<<<(800 * 128 + 255) / 256, 256, 0, stream>>>(Cacc, 800 * 128);
    k_gemm_mfma<<<dim3(1, 7, 16), 256, 0, stream>>>(Aconv, Bconv, nullptr,
        nullptr, nullptr, nullptr, nullptr, Cacc, nullptr,
        800, 128, 4608, 0, 0, 0, 0, 0, 16, 288);
    k_epi<<<(800 * 128 + 255) / 256, 256, 0, stream>>>(Cacc, c3b,
        g3, be3, m3, v3, y3, nullptr, 800, 128, 0, 1, 1, 1);

    // conv4: Cin=128 Kin=384, split-K x6 (42 blocks)
    k_split_im2col<<<dim3(2, 896), 256, 0, stream>>>(y3, Aconv, 128, 384);
    k_split_rows_b<<<dim3(2, 32), 256, 0, stream>>>(c4w, Bconv, 384);
    k_zero<<<(800 * 32 + 255) / 256, 256, 0, stream>>>(Cacc, 800 * 32);
    k_gemm_mfma<<<dim3(1, 7, 6), 256, 0, stream>>>(Aconv, Bconv, nullptr,
        nullptr, nullptr, nullptr, nullptr, Cacc, nullptr,
        800, 32, 1152, 0, 0, 0, 0, 0, 6, 192);
    k_epi<<<(800 * 32 + 255) / 256, 256, 0, stream>>>(Cacc, c4b,
        g4, be4, m4, v4, y4, nullptr, 800, 32, 0, 1, 1, 1);

    // final FCs (M=8 skinny)
    k_skinny<<<dim3(8, 2), 256, 0, stream>>>(y4, w15a, b15a, h2, 8, 512, 3200, 1);
    k_skinny<<<dim3(2, 2), 256, 0, stream>>>(h2, w15b, b15b, h3, 8, 128, 512, 1);
    k_skinny<<<dim3(1, 2), 256, 0, stream>>>(h3, w15c, b15c, out, 8, 15, 128, 0);
}

// Round 8
// 1452.229 us; speedup vs baseline: 1.9171x; 1.9171x over previous
//
#include <hip/hip_runtime.h>
#include <cstdint>

#define S64 64
#define S3 (S64*S64*S64)
#define NB 8
#define NPTS 2048

typedef unsigned short ushort_t;
typedef __attribute__((ext_vector_type(8))) short bh8;    // 8 bf16 (4 VGPRs)
typedef __attribute__((ext_vector_type(4))) float f4v;    // 4 fp32 acc

// ---- bf16 split helpers: a ~= hi + lo, each bf16 (RNE) ----
__device__ inline ushort_t bf_rne(float a) {
    unsigned u = __float_as_uint(a);
    unsigned r = (u + 0x7FFFu + ((u >> 16) & 1u)) >> 16;
    return (ushort_t)r;
}
__device__ inline void split2(float a, ushort_t& h, ushort_t& lo) {
    h = bf_rne(a);
    float hf = __uint_as_float(((unsigned)h) << 16);
    lo = bf_rne(a - hf);
}

// ---------------- Kernel 1: completion + gridding_reverse ----------------
__global__ void k_gridding(const float* __restrict__ data, float* __restrict__ pt_buf) {
    int idx = blockIdx.x * blockDim.x + threadIdx.x;
    if (idx >= NB * S3) return;
    int b = idx / S3;
    int cell = idx - b * S3;
    int i = cell >> 12;
    int j = (cell >> 6) & 63;
    int k = cell & 63;
    const float* db = data + (size_t)b * S3;
    float wsum = 0.f, px = 0.f, py = 0.f, pz = 0.f;
#pragma unroll
    for (int dx = 0; dx < 2; ++dx)
#pragma unroll
    for (int dy = 0; dy < 2; ++dy)
#pragma unroll
    for (int dz = 0; dz < 2; ++dz) {
        int xi = i + dx - 1, yj = j + dy - 1, zk = k + dz - 1;
        float w = 0.f;
        if (xi >= 0 && yj >= 0 && zk >= 0) {
            float v = db[((xi << 6) + yj << 6) + zk];
            w = (fabsf(v) <= 1.0f) ? 1.0f : 0.0f;
        }
        px += w * (float)xi;
        py += w * (float)yj;
        pz += w * (float)zk;
        wsum += w;
    }
    float wc = fmaxf(wsum, 1e-8f);
    float ptx = (px / wc) / 32.0f - 1.0f;
    float pty = (py / wc) / 32.0f - 1.0f;
    float ptz = (pz / wc) / 32.0f - 1.0f;
    if (!(wsum > 0.f)) { ptx = 0.f; pty = 0.f; ptz = 0.f; }
    float* o = pt_buf + (size_t)b * (S3 * 3) + (size_t)cell * 3;
    o[0] = ptx; o[1] = pty; o[2] = ptz;
}

// ---------------- Kernel 2: maxpool 4x4x4 ----------------
__global__ void k_maxpool(const float* __restrict__ pt_buf, float* __restrict__ pooled) {
    int idx = blockIdx.x * blockDim.x + threadIdx.x;
    if (idx >= NB * 12288) return;
    int b = idx / 12288;
    int r = idx - b * 12288;
    int c = r >> 12;
    int r2 = r & 4095;
    int X = r2 >> 8;
    int Y = (r2 >> 4) & 15;
    int Z = r2 & 15;
    const float* src = pt_buf + (size_t)b * (S3 * 3) + (size_t)c * S3;
    float m = -INFINITY;
#pragma unroll
    for (int u = 0; u < 4; ++u)
#pragma unroll
    for (int v = 0; v < 4; ++v)
#pragma unroll
    for (int w = 0; w < 4; ++w) {
        float val = src[((4 * X + u) << 12) + ((4 * Y + v) << 6) + (4 * Z + w)];
        m = fmaxf(m, val);
    }
    pooled[idx] = m;
}

// ---------------- Kernel 3: masked top-k + gather ----------------
__global__ void k_topk(const float* __restrict__ pooled, const float* __restrict__ noise,
                       float* __restrict__ sc) {
    __shared__ unsigned long long keys[4096];
    int b = blockIdx.x;
    int tid = threadIdx.x;
    for (int p = tid; p < 4096; p += 1024) {
        const float* cp = pooled + (size_t)b * 12288 + (size_t)p * 3;
        float ssum = (cp[0] + cp[1]) + cp[2];
        float score = (ssum != 0.0f) ? noise[b * 4096 + p] : -1e30f;
        unsigned int u = __float_as_uint(score);
        unsigned int s = (u & 0x80000000u) ? ~u : (u | 0x80000000u);
        keys[p] = ((unsigned long long)(~s) << 32) | (unsigned int)p;
    }
    __syncthreads();
    for (int k = 2; k <= 4096; k <<= 1) {
        for (int j = k >> 1; j > 0; j >>= 1) {
            for (int t = tid; t < 4096; t += 1024) {
                int ixj = t ^ j;
                if (ixj > t) {
                    bool up = ((t & k) == 0);
                    unsigned long long a = keys[t], c = keys[ixj];
                    if (up ? (a > c) : (a < c)) { keys[t] = c; keys[ixj] = a; }
                }
            }
            __syncthreads();
        }
    }
    for (int r = tid; r < NPTS; r += 1024) {
        int p = (int)(keys[r] & 0xFFFFFFFFu);
        const float* cp = pooled + (size_t)b * 12288 + (size_t)p * 3;
        float* o = sc + ((size_t)b * NPTS + r) * 3;
        o[0] = cp[0]; o[1] = cp[1]; o[2] = cp[2];
    }
}

// ---------------- Kernel 4: cubic feature sampling -> A' part triples ----------------
__global__ void k_cubic(const float* __restrict__ sc,
                        const float* __restrict__ s32,
                        const float* __restrict__ s16,
                        const float* __restrict__ s8,
                        ushort_t* __restrict__ Ap, int row0) {
    int rl = blockIdx.y;
    int row = row0 + rl;
    int col = blockIdx.x * 256 + threadIdx.x;  // 0..1791
    int b = row >> 11;
    const float* p = sc + (size_t)row * 3;
    float ptx = p[0], pty = p[1], ptz = p[2];
    const float* feat;
    int S, c, q;
    if (col < 256)      { S = 32; q = col >> 5;  c = col & 31;
                          feat = s32 + (size_t)b * 32 * 32768; }
    else if (col < 768) { int cc = col - 256; S = 16; q = cc >> 6; c = cc & 63;
                          feat = s16 + (size_t)b * 64 * 4096; }
    else                { int cc = col - 768; S = 8;  q = cc >> 7; c = cc & 127;
                          feat = s8 + (size_t)b * 128 * 512; }
    int dx = (q >> 2) & 1, dy = (q >> 1) & 1, dz = q & 1;
    float half = 0.5f * (float)S;
    int lx = (int)floorf((ptx + 1.0f) * half);
    int ly = (int)floorf((pty + 1.0f) * half);
    int lz = (int)floorf((ptz + 1.0f) * half);
    int ix = min(max(lx + dx, 0), S - 1);
    int iy = min(max(ly + dy, 0), S - 1);
    int iz = min(max(lz + dz, 0), S - 1);
    int lin = (ix * S + iy) * S + iz;
    float v = feat[(size_t)c * S * S * S + lin];
    ushort_t h, lo; split2(v, h, lo);
    size_t base = (size_t)rl * 5376 + 3 * (size_t)col;
    Ap[base] = h; Ap[base + 1] = h; Ap[base + 2] = lo;
}

// ---------------- split-convert: W[K][N] fp32 -> Bp[Npad][3K] (hi,lo,hi) ----------------
__global__ void k_split_transpose(const float* __restrict__ W, ushort_t* __restrict__ Bp,
                                  int K, int N, int Npad) {
    __shared__ float t[32][33];
    int tx = threadIdx.x, ty = threadIdx.y;   // (32,8)
    int n0 = blockIdx.x * 32, k0 = blockIdx.y * 32;
#pragma unroll
    for (int kk = 0; kk < 4; ++kk) {
        int k = k0 + ty + kk * 8, n = n0 + tx;
        float v = (k < K && n < N) ? W[(size_t)k * N + n] : 0.f;
        t[ty + kk * 8][tx] = v;
    }
    __syncthreads();
    size_t Kp = 3 * (size_t)K;
#pragma unroll
    for (int nn = 0; nn < 4; ++nn) {
        int n = n0 + ty + nn * 8;
        int k = k0 + tx;
        if (n >= Npad || k >= K) continue;
        float a = t[tx][ty + nn * 8];
        ushort_t h, lo; split2(a, h, lo);
        size_t base = (size_t)n * Kp + 3 * (size_t)k;
        Bp[base] = h; Bp[base + 1] = lo; Bp[base + 2] = h;
    }
}

// ---------------- split-convert rows: src[R][K] -> dst[R][3K], trip B (hi,lo,hi) --------
__global__ void k_split_rows_b(const float* __restrict__ src, ushort_t* __restrict__ dst, int K) {
    int r = blockIdx.y;
    int k = blockIdx.x * 256 + threadIdx.x;
    if (k >= K) return;
    float a = src[(size_t)r * K + k];
    ushort_t h, lo; split2(a, h, lo);
    size_t base = (size_t)r * (3 * (size_t)K) + 3 * (size_t)k;
    dst[base] = h; dst[base + 1] = lo; dst[base + 2] = h;
}

// ---------------- generic im2col + split (conv A-side) ----------------
__global__ void k_split_im2col(const float* __restrict__ src, ushort_t* __restrict__ Ap,
                               int Cin, int Kin) {
    int mp = blockIdx.y;                       // 0..895
    int k = blockIdx.x * 256 + threadIdx.x;
    if (k >= Kin) return;
    float v = 0.f;
    if (mp < 800) {
        int b = mp / 100, h = mp - b * 100;
        int c = k / 3, t = k - c * 3;
        int hh = h + t - 1;
        if (hh >= 0 && hh < 100)
            v = src[((size_t)b * Cin + c) * 100 + hh];
    }
    ushort_t h16, lo; split2(v, h16, lo);
    size_t base = (size_t)mp * (3 * (size_t)Kin) + 3 * (size_t)k;
    Ap[base] = h16; Ap[base + 1] = h16; Ap[base + 2] = lo;
}

// ---------------- zero kernel ----------------
__global__ void k_zero(float* __restrict__ p, int n) {
    int i = blockIdx.x * 256 + threadIdx.x;
    if (i < n) p[i] = 0.f;
}

// ---------------- epilogue for split-K accumulators ----------------
// mode 0: Cf[m*N+n] fp32; mode 1: conv layout; mode 2: triple-bf16 (hi,hi,lo) to Cs
__global__ void k_epi(const float* __restrict__ acc, const float* __restrict__ bias,
                      const float* __restrict__ bn_g, const float* __restrict__ bn_b,
                      const float* __restrict__ bn_m, const float* __restrict__ bn_v,
                      float* __restrict__ Cf, ushort_t* __restrict__ Cs,
                      int M, int N, int ldc, int relu, int dobn, int mode) {
    int idx = blockIdx.x * 256 + threadIdx.x;
    if (idx >= M * N) return;
    int m = idx / N, n = idx - m * N;
    float v = acc[idx] + bias[n];
    if (dobn) {
        float inv = rsqrtf(bn_v[n] + 1e-5f) * bn_g[n];
        v = v * inv + (bn_b[n] - bn_m[n] * inv);
    }
    if (relu) v = fmaxf(v, 0.f);
    if (mode == 0) {
        Cf[idx] = v;
    } else if (mode == 1) {
        int b = m / 100, h = m - b * 100;
        Cf[((size_t)b * N + n) * 100 + h] = v;
    } else {
        ushort_t h, lo; split2(v, h, lo);
        size_t base = (size_t)m * ldc + 3 * (size_t)n;
        Cs[base] = h; Cs[base + 1] = h; Cs[base + 2] = lo;
    }
}

// ---------------- MFMA bf16 GEMM, 2-phase dbuf + LDS XOR-swizzle + split-K ----------------
// Swizzle (rule #21 both-sides): LDS dest stays linear; global SOURCE quad is
// pre-swizzled (lc ^ (lr>>2)&3) so LDS[r][q] = G[r][q ^ ((r>>2)&3)]; reads use
// physical quad pq = jq ^ ((fr>>2)&3). 16 lanes -> 8 distinct 4-bank groups,
// 2 lanes each = conflict-free (2-way is free, m136).
#define GLDS(g, s) __builtin_amdgcn_global_load_lds( \
    (const __attribute__((address_space(1))) void*)(g), \
    (__attribute__((address_space(3))) void*)(s), 16, 0, 0)

__global__ __launch_bounds__(256) void k_gemm_mfma(
    const ushort_t* __restrict__ Ap, const ushort_t* __restrict__ Bp,
    const float* __restrict__ bias,
    const float* __restrict__ bn_g, const float* __restrict__ bn_b,
    const float* __restrict__ bn_m, const float* __restrict__ bn_v,
    float* __restrict__ Cf, ushort_t* __restrict__ Cs,
    int M, int N, int Kp, int ldc,
    int relu, int dobn, int omode, int osplit,
    int ks, int Kc)
{
    __shared__ short As[2][128][32];
    __shared__ short Bs[2][128][32];
    int tid = threadIdx.x;
    int l = tid & 63, w = tid >> 6;
    int wr = w >> 1, wc = w & 1;
    int m0 = blockIdx.y * 128, n0 = blockIdx.x * 128;
    int kbeg = blockIdx.z * Kc;       // Kc multiple of 32; ks*Kc == Kp

    f4v acc[4][4];
#pragma unroll
    for (int i = 0; i < 4; ++i)
#pragma unroll
        for (int j = 0; j < 4; ++j) acc[i][j] = (f4v){0.f, 0.f, 0.f, 0.f};

    int lr = l >> 2;                  // row within 16-row chunk
    int lc = l & 3;                   // logical 16B quad within 64B row
    int lcs = lc ^ ((lr >> 2) & 3);   // swizzled source quad
    const ushort_t* pa0 = Ap + (size_t)(m0 + w * 32 + lr) * Kp + lcs * 8 + kbeg;
    const ushort_t* pa1 = pa0 + (size_t)16 * Kp;
    const ushort_t* pb0 = Bp + (size_t)(n0 + w * 32 + lr) * Kp + lcs * 8 + kbeg;
    const ushort_t* pb1 = pb0 + (size_t)16 * Kp;

    int fr = l & 15;                          // fragment row/col index
    int ko = ((l >> 4) ^ ((fr >> 2) & 3)) * 8;  // swizzled LDS k-offset (elements)
    int nt = Kc >> 5;                         // tiles in this chunk

    // prologue: stage tile 0 into buffer 0
    GLDS(pa0, &As[0][w * 32][0]);
    GLDS(pa1, &As[0][w * 32 + 16][0]);
    GLDS(pb0, &Bs[0][w * 32][0]);
    GLDS(pb1, &Bs[0][w * 32 + 16][0]);
    __syncthreads();

    for (int t = 0; t < nt; ++t) {
        int cur = t & 1;
        if (t + 1 < nt) {
            int ko2 = (t + 1) << 5;
            GLDS(pa0 + ko2, &As[cur ^ 1][w * 32][0]);
            GLDS(pa1 + ko2, &As[cur ^ 1][w * 32 + 16][0]);
            GLDS(pb0 + ko2, &Bs[cur ^ 1][w * 32][0]);
            GLDS(pb1 + ko2, &Bs[cur ^ 1][w * 32 + 16][0]);
        }
        bh8 af[4], bfr[4];
#pragma unroll
        for (int i = 0; i < 4; ++i)
            af[i] = *reinterpret_cast<const bh8*>(&As[cur][wr * 64 + i * 16 + fr][ko]);
#pragma unroll
        for (int j = 0; j < 4; ++j)
            bfr[j] = *reinterpret_cast<const bh8*>(&Bs[cur][wc * 64 + j * 16 + fr][ko]);
#pragma unroll
        for (int i = 0; i < 4; ++i)
#pragma unroll
            for (int j = 0; j < 4; ++j)
                acc[i][j] = __builtin_amdgcn_mfma_f32_16x16x32_bf16(af[i], bfr[j], acc[i][j], 0, 0, 0);
        __syncthreads();
    }

    // epilogue: C/D mapping col=lane&15, row=(lane>>4)*4+reg  [verified m89/m91]
#pragma unroll
    for (int i = 0; i < 4; ++i)
#pragma unroll
        for (int j = 0; j < 4; ++j) {
#pragma unroll
            for (int r = 0; r < 4; ++r) {
                int m = m0 + wr * 64 + i * 16 + (l >> 4) * 4 + r;
                int n = n0 + wc * 64 + j * 16 + fr;
                if (m >= M || n >= N) continue;
                if (ks > 1) {
                    atomicAdd(&Cf[(size_t)m * N + n], acc[i][j][r]);
                    continue;
                }
                float v = acc[i][j][r] + bias[n];
                if (dobn) {
                    float inv = rsqrtf(bn_v[n] + 1e-5f) * bn_g[n];
                    v = v * inv + (bn_b[n] - bn_m[n] * inv);
                }
                if (relu) v = fmaxf(v, 0.f);
                if (osplit) {
                    ushort_t h, lo; split2(v, h, lo);
                    size_t base = (size_t)m * ldc + 3 * (size_t)n;
                    Cs[base] = h; Cs[base + 1] = h; Cs[base + 2] = lo;
                } else if (omode == 0) {
                    Cf[(size_t)m * N + n] = v;
                } else {
                    int bb = m / 100, h = m - bb * 100;
                    Cf[((size_t)bb * N + n) * 100 + h] = v;
                }
            }
        }
}

// ---------------- split-K skinny GEMM for M=8 final FCs ----------------
// grid (N/64, M/4, KS); wave -> one m, lane -> one n (coalesced B row reads,
// shared across the block's 4 waves via L1); atomicAdd partial into Cacc.
__global__ __launch_bounds__(256) void k_skinny2(
    const float* __restrict__ A, const float* __restrict__ B,
    float* __restrict__ Cacc, int M, int N, int K, int Kc)
{
    int lane = threadIdx.x & 63;
    int wv = threadIdx.x >> 6;
    int n = blockIdx.x * 64 + lane;
    int m = blockIdx.y * 4 + wv;
    if (m >= M || n >= N) return;
    int kbeg = blockIdx.z * Kc;
    int kend = min(K, kbeg + Kc);
    const float* a = A + (size_t)m * K;
    const float* b = B + n;
    float acc = 0.f;
#pragma unroll 4
    for (int k = kbeg; k < kend; ++k)
        acc = fmaf(a[k], b[(size_t)k * N], acc);
    atomicAdd(&Cacc[(size_t)m * N + n], acc);
}

// ---------------- launch ----------------
extern "C" void kernel_launch(void* const* d_in, const int* in_sizes, int n_in,
                              void* d_out, int out_size, void* d_ws, size_t ws_size,
                              hipStream_t stream) {
    const float* data  = (const float*)d_in[0];
    const float* s32   = (const float*)d_in[1];
    const float* s16   = (const float*)d_in[2];
    const float* s8    = (const float*)d_in[3];
    const float* noise = (const float*)d_in[4];
    const float* w11 = (const float*)d_in[5];  const float* b11 = (const float*)d_in[6];
    const float* w12 = (const float*)d_in[7];  const float* b12 = (const float*)d_in[8];
    const float* w13 = (const float*)d_in[9];  const float* b13 = (const float*)d_in[10];
    const float* c1w = (const float*)d_in[11]; const float* c1b = (const float*)d_in[12];
    const float* g1 = (const float*)d_in[13];  const float* be1 = (const float*)d_in[14];
    const float* m1 = (const float*)d_in[15];  const float* v1  = (const float*)d_in[16];
    const float* c2w = (const float*)d_in[17]; const float* c2b = (const float*)d_in[18];
    const float* g2 = (const float*)d_in[19];  const float* be2 = (const float*)d_in[20];
    const float* m2 = (const float*)d_in[21];  const float* v2  = (const float*)d_in[22];
    const float* c3w = (const float*)d_in[23]; const float* c3b = (const float*)d_in[24];
    const float* g3 = (const float*)d_in[25];  const float* be3 = (const float*)d_in[26];
    const float* m3 = (const float*)d_in[27];  const float* v3  = (const float*)d_in[28];
    const float* c4w = (const float*)d_in[29]; const float* c4b = (const float*)d_in[30];
    const float* g4 = (const float*)d_in[31];  const float* be4 = (const float*)d_in[32];
    const float* m4 = (const float*)d_in[33];  const float* v4  = (const float*)d_in[34];
    const float* w15a = (const float*)d_in[35]; const float* b15a = (const float*)d_in[36];
    const float* w15b = (const float*)d_in[37]; const float* b15b = (const float*)d_in[38];
    const float* w15c = (const float*)d_in[39]; const float* b15c = (const float*)d_in[40];
    float* out = (float*)d_out;
    (void)in_sizes; (void)n_in; (void)out_size;

    char* ws = (char*)d_ws;

    // adaptive partition: halves (P=8192, ~251MB) if ws fits, else quarters (P=4096, ~145MB)
    size_t offs[16];
    auto plan = [&](size_t P, size_t* o) -> size_t {
        size_t off = 0;
        auto al = [&](size_t b) { size_t x = off; off += (b + 255) & ~(size_t)255; return x; };
        o[0]  = al(P * 5376 * 2);          // rA: pt_buf -> A' part -> conv A' triples
        o[1]  = al(P * 5376 * 2);          // rF: f2' part -> conv B' triples
        o[2]  = al(P * 1344 * 2);          // rG: f3' part (FC3 A-triples)
        o[3]  = al((size_t)1792 * 5376 * 2); // B'1
        o[4]  = al((size_t)512 * 5376 * 2);  // B'2
        o[5]  = al((size_t)128 * 1344 * 2);  // B'3
        o[6]  = al(P * 448 * 4);           // split-K accumulator (>= 800*1024*4)
        o[7]  = al((size_t)16384 * 100 * 4); // f4
        o[8]  = al((size_t)NB * 1024 * 100 * 4); // y1
        o[9]  = al((size_t)NB * 512 * 100 * 4);  // y2
        o[10] = al((size_t)NB * 128 * 100 * 4);  // y3
        o[11] = al((size_t)NB * 32 * 100 * 4);   // y4
        o[12] = al(NB * 12288 * 4);        // pooled
        o[13] = al(NB * NPTS * 3 * 4);     // sc
        o[14] = al(NB * 512 * 4);          // h2
        o[15] = al(NB * 128 * 4);          // h3
        return off;
    };
    size_t P = 8192;
    if (plan(P, offs) > ws_size) P = 4096;
    plan(P, offs);
    int nparts = (int)(16384 / P);
    int Pb = (int)(P / 128);                  // row blocks per part
    int ksFC2 = (P == 8192) ? 2 : 4;
    int KcFC2 = 5376 / ksFC2;

    float*    pt_buf = (float*)(ws + offs[0]);
    ushort_t* Aq     = (ushort_t*)(ws + offs[0]);
    ushort_t* Aconv  = (ushort_t*)(ws + offs[0]);
    ushort_t* Fq     = (ushort_t*)(ws + offs[1]);
    ushort_t* Bconv  = (ushort_t*)(ws + offs[1]);
    ushort_t* Gq     = (ushort_t*)(ws + offs[2]);
    ushort_t* Bp1    = (ushort_t*)(ws + offs[3]);
    ushort_t* Bp2    = (ushort_t*)(ws + offs[4]);
    ushort_t* Bp3    = (ushort_t*)(ws + offs[5]);
    float*    Cacc   = (float*)(ws + offs[6]);
    float* f4     = (float*)(ws + offs[7]);
    float* y1     = (float*)(ws + offs[8]);
    float* y2     = (float*)(ws + offs[9]);
    float* y3     = (float*)(ws + offs[10]);
    float* y4     = (float*)(ws + offs[11]);
    float* pooled = (float*)(ws + offs[12]);
    float* scb    = (float*)(ws + offs[13]);
    float* h2     = (float*)(ws + offs[14]);
    float* h3     = (float*)(ws + offs[15]);

    // front-end
    k_gridding<<<(NB * S3 + 255) / 256, 256, 0, stream>>>(data, pt_buf);
    k_maxpool<<<(NB * 12288 + 255) / 256, 256, 0, stream>>>(pt_buf, pooled);
    k_topk<<<NB, 1024, 0, stream>>>(pooled, noise, scb);

    // weight triples for FC1..FC3
    k_split_transpose<<<dim3(56, 56), dim3(32, 8), 0, stream>>>(w11, Bp1, 1792, 1792, 1792);
    k_split_transpose<<<dim3(16, 56), dim3(32, 8), 0, stream>>>(w12, Bp2, 1792, 448, 512);
    k_split_transpose<<<dim3(4, 14),  dim3(32, 8), 0, stream>>>(w13, Bp3, 448, 100, 128);

    // FC1 + FC2 + FC3 in parts of P rows
    for (int q = 0; q < nparts; ++q) {
        k_cubic<<<dim3(7, (unsigned)P), 256, 0, stream>>>(scb, s32, s16, s8, Aq, q * (int)P);
        // FC1: direct, triple-bf16 out
        k_gemm_mfma<<<dim3(14, Pb), 256, 0, stream>>>(Aq, Bp1, b11,
            nullptr, nullptr, nullptr, nullptr, nullptr, Fq,
            (int)P, 1792, 5376, 5376, 1, 0, 0, 1, 1, 5376);
        // FC2: split-K, epilogue -> Gq triples
        k_zero<<<((int)P * 448 + 255) / 256, 256, 0, stream>>>(Cacc, (int)P * 448);
        k_gemm_mfma<<<dim3(4, Pb, ksFC2), 256, 0, stream>>>(Fq, Bp2, nullptr,
            nullptr, nullptr, nullptr, nullptr, Cacc, nullptr,
            (int)P, 448, 5376, 0, 0, 0, 0, 0, ksFC2, KcFC2);
        k_epi<<<((int)P * 448 + 255) / 256, 256, 0, stream>>>(Cacc, b12,
            nullptr, nullptr, nullptr, nullptr, nullptr, Gq,
            (int)P, 448, 1344, 1, 0, 2);
        // FC3: split-K x6, epilogue -> f4 slice fp32
        k_zero<<<((int)P * 100 + 255) / 256, 256, 0, stream>>>(Cacc, (int)P * 100);
        k_gemm_mfma<<<dim3(1, Pb, 6), 256, 0, stream>>>(Gq, Bp3, nullptr,
            nullptr, nullptr, nullptr, nullptr, Cacc, nullptr,
            (int)P, 100, 1344, 0, 0, 0, 0, 0, 6, 224);
        k_epi<<<((int)P * 100 + 255) / 256, 256, 0, stream>>>(Cacc, b13,
            nullptr, nullptr, nullptr, nullptr, f4 + (size_t)q * P * 100, nullptr,
            (int)P, 100, 0, 1, 0, 0);
    }

    // conv1: Cin=2048 Kin=6144, split-K x8 (448 blocks)
    k_split_im2col<<<dim3(24, 896), 256, 0, stream>>>(f4, Aconv, 2048, 6144);
    k_split_rows_b<<<dim3(24, 1024), 256, 0, stream>>>(c1w, Bconv, 6144);
    k_zero<<<(800 * 1024 + 255) / 256, 256, 0, stream>>>(Cacc, 800 * 1024);
    k_gemm_mfma<<<dim3(8, 7, 8), 256, 0, stream>>>(Aconv, Bconv, nullptr,
        nullptr, nullptr, nullptr, nullptr, Cacc, nullptr,
        800, 1024, 18432, 0, 0, 0, 0, 0, 8, 2304);
    k_epi<<<(800 * 1024 + 255) / 256, 256, 0, stream>>>(Cacc, c1b,
        g1, be1, m1, v1, y1, nullptr, 800, 1024, 0, 1, 1, 1);

    // conv2: Cin=1024 Kin=3072, split-K x8 (224 blocks)
    k_split_im2col<<<dim3(12, 896), 256, 0, stream>>>(y1, Aconv, 1024, 3072);
    k_split_rows_b<<<dim3(12, 512), 256, 0, stream>>>(c2w, Bconv, 3072);
    k_zero<<<(800 * 512 + 255) / 256, 256, 0, stream>>>(Cacc, 800 * 512);
    k_gemm_mfma<<<dim3(4, 7, 8), 256, 0, stream>>>(Aconv, Bconv, nullptr,
        nullptr, nullptr, nullptr, nullptr, Cacc, nullptr,
        800, 512, 9216, 0, 0, 0, 0, 0, 8, 1152);
    k_epi<<<(800 * 512 + 255) / 256, 256, 0, stream>>>(Cacc, c2b,
        g2, be2, m2, v2, y2, nullptr, 800, 512, 0, 1, 1, 1);

    // conv3: Cin=512 Kin=1536, split-K x16 (112 blocks)
    k_split_im2col<<<dim3(6, 896), 256, 0, stream>>>(y2, Aconv, 512, 1536);
    k_split_rows_b<<<dim3(6, 128), 256, 0, stream>>>(c3w, Bconv, 1536);
    k_zero<<<(800 * 128 + 255) / 256, 256, 0, stream>>>(Cacc, 800 * 128);
    k_gemm_mfma<<<dim3(1, 7, 16), 256, 0, stream>>>(Aconv, Bconv, nullptr,
        nullptr, nullptr, nullptr, nullptr, Cacc, nullptr,
        800, 128, 4608, 0, 0, 0, 0, 0, 16, 288);
    k_epi<<<(800 * 128 + 255) / 256, 256, 0, stream>>>(Cacc, c3b,
        g3, be3, m3, v3, y3, nullptr, 800, 128, 0, 1, 1, 1);

    // conv4: Cin=128 Kin=384, split-K x6 (42 blocks)
    k_split_im2col<<<dim3(2, 896), 256, 0, stream>>>(y3, Aconv, 128, 384);
    k_split_rows_b<<<dim3(2, 32), 256, 0, stream>>>(c4w, Bconv, 384);
    k_zero<<<(800 * 32 + 255) / 256, 256, 0, stream>>>(Cacc, 800 * 32);
    k_gemm_mfma<<<dim3(1, 7, 6), 256, 0, stream>>>(Aconv, Bconv, nullptr,
        nullptr, nullptr, nullptr, nullptr, Cacc, nullptr,
        800, 32, 1152, 0, 0, 0, 0, 0, 6, 192);
    k_epi<<<(800 * 32 + 255) / 256, 256, 0, stream>>>(Cacc, c4b,
        g4, be4, m4, v4, y4, nullptr, 800, 32, 0, 1, 1, 1);

    // final FCs (M=8): split-K skinny + epilogue
    // FC15a: N=512 K=3200, KS=32 (512 blocks)
    k_zero<<<(8 * 512 + 255) / 256, 256, 0, stream>>>(Cacc, 8 * 512);
    k_skinny2<<<dim3(8, 2, 32), 256, 0, stream>>>(y4, w15a, Cacc, 8, 512, 3200, 100);
    k_epi<<<(8 * 512 + 255) / 256, 256, 0, stream>>>(Cacc, b15a,
        nullptr, nullptr, nullptr, nullptr, h2, nullptr, 8, 512, 0, 1, 0, 0);
    // FC15b: N=128 K=512, KS=8 (32 blocks)
    k_zero<<<(8 * 128 + 255) / 256, 256, 0, stream>>>(Cacc, 8 * 128);
    k_skinny2<<<dim3(2, 2, 8), 256, 0, stream>>>(h2, w15b, Cacc, 8, 128, 512, 64);
    k_epi<<<(8 * 128 + 255) / 256, 256, 0, stream>>>(Cacc, b15b,
        nullptr, nullptr, nullptr, nullptr, h3, nullptr, 8, 128, 0, 1, 0, 0);
    // FC15c: N=15 K=128, KS=2 (4 blocks)
    k_zero<<<(8 * 15 + 255) / 256, 256, 0, stream>>>(Cacc, 8 * 15);
    k_skinny2<<<dim3(1, 2, 2), 256, 0, stream>>>(h3, w15c, Cacc, 8, 15, 128, 64);
    k_epi<<<(8 * 15 + 255) / 256, 256, 0, stream>>>(Cacc, b15c,
        nullptr, nullptr, nullptr, nullptr, out, nullptr, 8, 15, 0, 0, 0, 0);
}